// Round 2
// baseline (959.668 us; speedup 1.0000x reference)
//
#include <hip/hip_runtime.h>
#include <hip/hip_bf16.h>
#include <math.h>

#define SCAN_CHUNK 4096

__device__ __forceinline__ float lrelu(float x){ return x < 0.f ? 0.2f*x : x; }
__device__ __forceinline__ float elu_(float x){ return x > 0.f ? x : expm1f(x); }

// ---------------- CSR build ----------------
__global__ void khist(const int* __restrict__ ei, int E, int Etot, int* __restrict__ deg){
  int i = blockIdx.x*blockDim.x + threadIdx.x;
  if (i >= Etot) return;
  int dst = (i < E) ? ei[E + i] : (i - E);
  atomicAdd(&deg[dst], 1);
}

__global__ void kscan1(const int* __restrict__ deg, int n, int* __restrict__ bsum){
  __shared__ int wsum[4];
  int blk = blockIdx.x, tid = threadIdx.x;
  int base = blk*SCAN_CHUNK + tid*16;
  int s = 0;
  #pragma unroll
  for (int j=0;j<16;j++){ int idx = base+j; if (idx < n) s += deg[idx]; }
  for (int m=1;m<64;m<<=1) s += __shfl_xor(s, m);
  if ((tid&63)==0) wsum[tid>>6] = s;
  __syncthreads();
  if (tid==0) bsum[blk] = wsum[0]+wsum[1]+wsum[2]+wsum[3];
}

__global__ void kscan2(const int* __restrict__ bsum, int* __restrict__ bpre, int nb,
                       int* __restrict__ off, int n, int Etot){
  if (threadIdx.x==0 && blockIdx.x==0){
    int run = 0;
    for (int i=0;i<nb;i++){ bpre[i] = run; run += bsum[i]; }
    off[n] = Etot;
  }
}

__global__ void kscan3(const int* __restrict__ deg, int n, const int* __restrict__ bpre,
                       int* __restrict__ off, int* __restrict__ cursor){
  __shared__ int wtot[4];
  int blk = blockIdx.x, tid = threadIdx.x, lane = tid & 63, w = tid >> 6;
  int base = blk*SCAN_CHUNK + tid*16;
  int v[16]; int s = 0;
  #pragma unroll
  for (int j=0;j<16;j++){ int idx = base+j; v[j] = (idx<n) ? deg[idx] : 0; s += v[j]; }
  int x = s;
  for (int d=1; d<64; d<<=1){ int y = __shfl_up(x, d); if (lane >= (int)d) x += y; }
  int texcl = x - s;
  if (lane == 63) wtot[w] = x;
  __syncthreads();
  int wprefix = 0;
  for (int i=0;i<w;i++) wprefix += wtot[i];
  int run = bpre[blk] + wprefix + texcl;
  #pragma unroll
  for (int j=0;j<16;j++){
    int idx = base+j;
    if (idx < n){ off[idx] = run; cursor[idx] = run; run += v[j]; }
  }
}

__global__ void kscatter(const int* __restrict__ ei, int E, int Etot,
                         int* __restrict__ cursor, int* __restrict__ srcs){
  int i = blockIdx.x*blockDim.x + threadIdx.x;
  if (i >= Etot) return;
  int s, d;
  if (i < E){ s = ei[i]; d = ei[E+i]; } else { s = i-E; d = i-E; }
  int p = atomicAdd(&cursor[d], 1);
  srcs[p] = s;
}

// ---------------- fused (gather) + GEMM(128x128) + attention-logit reductions ----------------
// Block: 256 threads = 64 col-pairs x 4 row-slots. 32 rows per block.
template<int H, bool GATHER>
__global__ __launch_bounds__(256) void gemm_al(
    const float* __restrict__ X, const int* __restrict__ idx,
    const float* __restrict__ W, const float* __restrict__ asrc,
    const float* __restrict__ adst, float* __restrict__ Hout,
    float* __restrict__ als, float* __restrict__ ald, int n)
{
  __shared__ float xs[32][128];
  __shared__ float wch[32][128];
  int tid = threadIdx.x;
  int c2 = tid & 63, slot = tid >> 6;
  int c0 = 2*c2, c1 = c0+1;
  int row0 = blockIdx.x * 32;

  #pragma unroll
  for (int j=0;j<16;j++){
    int e = tid + j*256;
    int r = e >> 7, c = e & 127;
    int gr = row0 + r;
    float vv = 0.f;
    if (gr < n){
      int srow = GATHER ? idx[gr] : gr;
      vv = X[(size_t)srow*128 + c];
    }
    xs[r][c] = vv;
  }

  float acc[8][2];
  #pragma unroll
  for (int r=0;r<8;r++){ acc[r][0]=0.f; acc[r][1]=0.f; }

  for (int kc=0;kc<4;kc++){
    __syncthreads();
    #pragma unroll
    for (int j=0;j<16;j++){
      int e = tid + j*256;
      int r = e>>7, c = e&127;
      wch[r][c] = W[(size_t)(kc*32+r)*128 + c];
    }
    __syncthreads();
    #pragma unroll
    for (int kk=0;kk<32;kk++){
      const float2 wv = *reinterpret_cast<const float2*>(&wch[kk][c0]);
      #pragma unroll
      for (int r=0;r<8;r++){
        float xv = xs[slot + 4*r][kc*32+kk];
        acc[r][0] = fmaf(xv, wv.x, acc[r][0]);
        acc[r][1] = fmaf(xv, wv.y, acc[r][1]);
      }
    }
  }

  const int GS = 64 / H;   // lanes per head group (H=4 -> 16, H=1 -> 64)
  float asrc0 = asrc[c0], asrc1 = asrc[c1];
  float adst0 = adst[c0], adst1 = adst[c1];
  int lane = c2;

  #pragma unroll
  for (int r=0;r<8;r++){
    int gr = row0 + slot + 4*r;
    if (gr < n){
      Hout[(size_t)gr*128 + c0] = acc[r][0];
      Hout[(size_t)gr*128 + c1] = acc[r][1];
    }
    float ps = acc[r][0]*asrc0 + acc[r][1]*asrc1;
    float pd = acc[r][0]*adst0 + acc[r][1]*adst1;
    #pragma unroll
    for (int m=1;m<GS;m<<=1){ ps += __shfl_xor(ps,m); pd += __shfl_xor(pd,m); }
    if ((lane & (GS-1)) == 0 && gr < n){
      int hh = lane / GS;
      als[(size_t)gr*H + hh] = ps;
      ald[(size_t)gr*H + hh] = pd;
    }
  }
}

// ---------------- per-dst segment softmax + weighted aggregation ----------------
// one 64-lane wave per destination node; 2 channels per lane.
template<int H>
__global__ __launch_bounds__(256) void aggr(
    const float* __restrict__ h, const float* __restrict__ als,
    const float* __restrict__ ald, const int* __restrict__ srcs,
    const int* __restrict__ off, const float* __restrict__ bias,
    float* __restrict__ out, int n)
{
  int tid = threadIdx.x;
  int d = blockIdx.x*4 + (tid>>6);
  if (d >= n) return;
  int lane = tid & 63;
  int c0 = 2*lane, c1 = c0+1;
  int hh = (lane * H) >> 6;          // head index for this lane's channels
  float aldv = ald[(size_t)d*H + hh];
  int s0 = off[d], s1 = off[d+1];

  float m = -INFINITY;
  for (int i=s0;i<s1;i++){
    int s = srcs[i];
    float e = lrelu(als[(size_t)s*H + hh] + aldv);
    m = fmaxf(m, e);
  }
  float ssum=0.f, a0=0.f, a1=0.f;
  for (int i=s0;i<s1;i++){
    int s = srcs[i];
    float e = lrelu(als[(size_t)s*H + hh] + aldv);
    float wgt = __expf(e - m);
    ssum += wgt;
    const float2 hv = *reinterpret_cast<const float2*>(&h[(size_t)s*128 + c0]);
    a0 = fmaf(wgt, hv.x, a0);
    a1 = fmaf(wgt, hv.y, a1);
  }
  float inv = 1.f / ssum;
  out[(size_t)d*128 + c0] = elu_(a0*inv + bias[c0]);
  out[(size_t)d*128 + c1] = elu_(a1*inv + bias[c1]);
}

// ---------------- global mean pool (batch is sorted) ----------------
__global__ __launch_bounds__(256) void kpool(const float* __restrict__ act,
    const int* __restrict__ batch, int n, float* __restrict__ pool)
{
  __shared__ int sb[2];
  __shared__ float part[128];
  int g = blockIdx.x, tid = threadIdx.x;
  if (tid == 0){
    int lo=0, hi=n;
    while (lo<hi){ int mid=(lo+hi)>>1; if (batch[mid] < g) lo=mid+1; else hi=mid; }
    sb[0]=lo;
    int lo2=lo, hi2=n;
    while (lo2<hi2){ int mid=(lo2+hi2)>>1; if (batch[mid] < g+1) lo2=mid+1; else hi2=mid; }
    sb[1]=lo2;
  }
  __syncthreads();
  int lo=sb[0], hi=sb[1];
  int c = tid & 127, half = tid >> 7;
  float acc = 0.f;
  for (int i=lo+half; i<hi; i+=2) acc += act[(size_t)i*128 + c];
  if (half == 0) part[c] = acc;
  __syncthreads();
  if (half == 1) part[c] += acc;
  __syncthreads();
  if (half == 0){
    float cnt = (float)(hi-lo);
    pool[(size_t)g*128 + c] = part[c] / fmaxf(cnt, 1.f);
  }
}

// ---------------- classifier head: relu(hp@Wc1+bc1)@Wc2+bc2 ----------------
__global__ __launch_bounds__(64) void kclassify(const float* __restrict__ pool,
    const float* __restrict__ Wc1, const float* __restrict__ bc1,
    const float* __restrict__ Wc2, const float* __restrict__ bc2,
    float* __restrict__ logits)
{
  int g = blockIdx.x, j = threadIdx.x;
  const float* hp = pool + (size_t)g*128;
  float t = bc1[j];
  #pragma unroll 8
  for (int c=0;c<128;c++) t = fmaf(hp[c], Wc1[c*64+j], t);
  t = fmaxf(t, 0.f) * Wc2[j];
  for (int m=1;m<64;m<<=1) t += __shfl_xor(t, m);
  if (j==0) logits[g] = t + bc2[0];
}

extern "C" void kernel_launch(void* const* d_in, const int* in_sizes, int n_in,
                              void* d_out, int out_size, void* d_ws, size_t ws_size,
                              hipStream_t stream)
{
  const int*   x_lex = (const int*)d_in[0];
  const int*   ei    = (const int*)d_in[1];
  const int*   batch = (const int*)d_in[2];
  const float* emb   = (const float*)d_in[3];
  const float* W1    = (const float*)d_in[4];
  const float* a1s   = (const float*)d_in[5];
  const float* a1d   = (const float*)d_in[6];
  const float* b1    = (const float*)d_in[7];
  const float* W2    = (const float*)d_in[8];
  const float* a2s   = (const float*)d_in[9];
  const float* a2d   = (const float*)d_in[10];
  const float* b2    = (const float*)d_in[11];
  const float* Wc1   = (const float*)d_in[12];
  const float* bc1   = (const float*)d_in[13];
  const float* Wc2   = (const float*)d_in[14];
  const float* bc2   = (const float*)d_in[15];

  int N = in_sizes[0];
  int E = in_sizes[1] / 2;
  int Etot = E + N;
  const int G = 256;

  char* p = (char*)d_ws;
  float* hbuf = (float*)p;            p += (size_t)N*128*4;
  float* act  = (float*)p;            p += (size_t)N*128*4;
  float* als  = (float*)p;            p += (size_t)N*4*4;
  float* ald  = (float*)p;            p += (size_t)N*4*4;
  int* deg    = (int*)p;              p += (size_t)N*4;
  int* off    = (int*)p;              p += (size_t)(N+1)*4;
  int* cursor = (int*)p;              p += (size_t)N*4;
  int* bsum   = (int*)p;              p += 256*4;
  int* bpre   = (int*)p;              p += 256*4;
  int* srcs   = (int*)p;              /* Etot ints */

  // ---- CSR build (shared by both GAT layers) ----
  hipMemsetAsync(deg, 0, (size_t)N*4, stream);
  int eb = (Etot + 255)/256;
  khist<<<eb,256,0,stream>>>(ei, E, Etot, deg);
  int nb = (N + SCAN_CHUNK-1)/SCAN_CHUNK;
  kscan1<<<nb,256,0,stream>>>(deg, N, bsum);
  kscan2<<<1,64,0,stream>>>(bsum, bpre, nb, off, N, Etot);
  kscan3<<<nb,256,0,stream>>>(deg, N, bpre, off, cursor);
  kscatter<<<eb,256,0,stream>>>(ei, E, Etot, cursor, srcs);

  // ---- layer 1: h = emb[x_lex] @ W1, 4 heads ----
  int gb = (N + 31)/32;
  gemm_al<4,true ><<<gb,256,0,stream>>>(emb, x_lex, W1, a1s, a1d, hbuf, als, ald, N);
  aggr<4><<<(N+3)/4,256,0,stream>>>(hbuf, als, ald, srcs, off, b1, act, N);

  // ---- layer 2: h2 = act @ W2, 1 head ----
  gemm_al<1,false><<<gb,256,0,stream>>>(act, nullptr, W2, a2s, a2d, hbuf, als, ald, N);
  aggr<1><<<(N+3)/4,256,0,stream>>>(hbuf, als, ald, srcs, off, b2, act, N);

  // ---- pool + classifier ----
  float* out = (float*)d_out;
  kpool<<<G,256,0,stream>>>(act, batch, N, out + G);
  kclassify<<<G,64,0,stream>>>(out + G, Wc1, bc1, Wc2, bc2, out);
}

// Round 5
// 698.789 us; speedup vs baseline: 1.3733x; 1.3733x over previous
//
#include <hip/hip_runtime.h>
#include <hip/hip_bf16.h>
#include <math.h>

#define SCAN_CHUNK 4096

__device__ __forceinline__ float lrelu(float x){ return x < 0.f ? 0.2f*x : x; }
__device__ __forceinline__ float elu_(float x){ return x > 0.f ? x : expm1f(x); }

// ---------------- CSR build ----------------
__global__ void khist(const int* __restrict__ ei, int E, int Etot, int* __restrict__ deg){
  int i = blockIdx.x*blockDim.x + threadIdx.x;
  if (i >= Etot) return;
  int dst = (i < E) ? ei[E + i] : (i - E);
  atomicAdd(&deg[dst], 1);
}

__global__ void kscan1(const int* __restrict__ deg, int n, int* __restrict__ bsum){
  __shared__ int wsum[4];
  int blk = blockIdx.x, tid = threadIdx.x;
  int base = blk*SCAN_CHUNK + tid*16;
  int s = 0;
  #pragma unroll
  for (int j=0;j<16;j++){ int idx = base+j; if (idx < n) s += deg[idx]; }
  for (int m=1;m<64;m<<=1) s += __shfl_xor(s, m);
  if ((tid&63)==0) wsum[tid>>6] = s;
  __syncthreads();
  if (tid==0) bsum[blk] = wsum[0]+wsum[1]+wsum[2]+wsum[3];
}

__global__ void kscan2(const int* __restrict__ bsum, int* __restrict__ bpre, int nb,
                       int* __restrict__ off, int n, int Etot){
  if (threadIdx.x==0 && blockIdx.x==0){
    int run = 0;
    for (int i=0;i<nb;i++){ bpre[i] = run; run += bsum[i]; }
    off[n] = Etot;
  }
}

__global__ void kscan3(const int* __restrict__ deg, int n, const int* __restrict__ bpre,
                       int* __restrict__ off, int* __restrict__ cursor){
  __shared__ int wtot[4];
  int blk = blockIdx.x, tid = threadIdx.x, lane = tid & 63, w = tid >> 6;
  int base = blk*SCAN_CHUNK + tid*16;
  int v[16]; int s = 0;
  #pragma unroll
  for (int j=0;j<16;j++){ int idx = base+j; v[j] = (idx<n) ? deg[idx] : 0; s += v[j]; }
  int x = s;
  for (int d=1; d<64; d<<=1){ int y = __shfl_up(x, d); if (lane >= (int)d) x += y; }
  int texcl = x - s;
  if (lane == 63) wtot[w] = x;
  __syncthreads();
  int wprefix = 0;
  for (int i=0;i<w;i++) wprefix += wtot[i];
  int run = bpre[blk] + wprefix + texcl;
  #pragma unroll
  for (int j=0;j<16;j++){
    int idx = base+j;
    if (idx < n){ off[idx] = run; cursor[idx] = run; run += v[j]; }
  }
}

__global__ void kscatter(const int* __restrict__ ei, int E, int Etot,
                         int* __restrict__ cursor, int* __restrict__ srcs){
  int i = blockIdx.x*blockDim.x + threadIdx.x;
  if (i >= Etot) return;
  int s, d;
  if (i < E){ s = ei[i]; d = ei[E+i]; } else { s = i-E; d = i-E; }
  int p = atomicAdd(&cursor[d], 1);
  srcs[p] = s;
}

// ---------------- fused (gather) + GEMM(128x128) + attention-logit reductions ----------------
template<int H, bool GATHER>
__global__ __launch_bounds__(256) void gemm_al(
    const float* __restrict__ X, const int* __restrict__ idx,
    const float* __restrict__ W, const float* __restrict__ asrc,
    const float* __restrict__ adst, float* __restrict__ Hout,
    float* __restrict__ als, float* __restrict__ ald, int n)
{
  __shared__ float xs[32][128];
  __shared__ float wch[32][128];
  int tid = threadIdx.x;
  int c2 = tid & 63, slot = tid >> 6;
  int c0 = 2*c2, c1 = c0+1;
  int row0 = blockIdx.x * 32;

  #pragma unroll
  for (int j=0;j<16;j++){
    int e = tid + j*256;
    int r = e >> 7, c = e & 127;
    int gr = row0 + r;
    float vv = 0.f;
    if (gr < n){
      int srow = GATHER ? idx[gr] : gr;
      vv = X[(size_t)srow*128 + c];
    }
    xs[r][c] = vv;
  }

  float acc[8][2];
  #pragma unroll
  for (int r=0;r<8;r++){ acc[r][0]=0.f; acc[r][1]=0.f; }

  for (int kc=0;kc<4;kc++){
    __syncthreads();
    #pragma unroll
    for (int j=0;j<16;j++){
      int e = tid + j*256;
      int r = e>>7, c = e&127;
      wch[r][c] = W[(size_t)(kc*32+r)*128 + c];
    }
    __syncthreads();
    #pragma unroll
    for (int kk=0;kk<32;kk++){
      const float2 wv = *reinterpret_cast<const float2*>(&wch[kk][c0]);
      #pragma unroll
      for (int r=0;r<8;r++){
        float xv = xs[slot + 4*r][kc*32+kk];
        acc[r][0] = fmaf(xv, wv.x, acc[r][0]);
        acc[r][1] = fmaf(xv, wv.y, acc[r][1]);
      }
    }
  }

  const int GS = 64 / H;
  float asrc0 = asrc[c0], asrc1 = asrc[c1];
  float adst0 = adst[c0], adst1 = adst[c1];
  int lane = c2;

  #pragma unroll
  for (int r=0;r<8;r++){
    int gr = row0 + slot + 4*r;
    if (gr < n){
      Hout[(size_t)gr*128 + c0] = acc[r][0];
      Hout[(size_t)gr*128 + c1] = acc[r][1];
    }
    float ps = acc[r][0]*asrc0 + acc[r][1]*asrc1;
    float pd = acc[r][0]*adst0 + acc[r][1]*adst1;
    #pragma unroll
    for (int m=1;m<GS;m<<=1){ ps += __shfl_xor(ps,m); pd += __shfl_xor(pd,m); }
    if ((lane & (GS-1)) == 0 && gr < n){
      int hh = lane / GS;
      als[(size_t)gr*H + hh] = ps;
      ald[(size_t)gr*H + hh] = pd;
    }
  }
}

// ---------------- per-dst segment softmax + weighted aggregation ----------------
// One 64-lane wave per destination node. Wave-cooperative: lanes act as
// edges for the softmax (coalesced srcs load + shfl butterflies), then as
// channels for the accumulate (weights staged in LDS; h-row gathers are
// independent -> deep pipelining). Online-softmax chunking handles deg>64.
template<int H>
__global__ __launch_bounds__(256) void aggr(
    const float* __restrict__ h, const float* __restrict__ als,
    const float* __restrict__ ald, const int* __restrict__ srcs,
    const int* __restrict__ off, const float* __restrict__ bias,
    float* __restrict__ out, int n)
{
  __shared__ float s_p[4][64*H];
  __shared__ int   s_s[4][64];
  int tid = threadIdx.x;
  int wid = tid >> 6, lane = tid & 63;
  int d = blockIdx.x*4 + wid;
  if (d >= n) return;
  int c0 = 2*lane, c1 = c0+1;
  const int hh = (H==1) ? 0 : (lane >> 4);   // head owning channels c0,c1

  int s0 = off[d], s1 = off[d+1];

  float adv[H];
  #pragma unroll
  for (int q=0;q<H;q++) adv[q] = ald[(size_t)d*H + q];

  float m[H], ssum[H];
  #pragma unroll
  for (int q=0;q<H;q++){ m[q] = -INFINITY; ssum[q] = 0.f; }
  float a0 = 0.f, a1 = 0.f;

  for (int base = s0; base < s1; base += 64){
    int cl = s1 - base; if (cl > 64) cl = 64;

    int sv = 0;
    float e[H];
    if (lane < cl){
      sv = srcs[base + lane];
      #pragma unroll
      for (int q=0;q<H;q++) e[q] = lrelu(als[(size_t)sv*H + q] + adv[q]);
    } else {
      #pragma unroll
      for (int q=0;q<H;q++) e[q] = -INFINITY;
    }

    // chunk max per head (all 64 lanes participate; inactive = -INF)
    float cm[H];
    #pragma unroll
    for (int q=0;q<H;q++) cm[q] = e[q];
    #pragma unroll
    for (int sh=1; sh<64; sh<<=1){
      #pragma unroll
      for (int q=0;q<H;q++) cm[q] = fmaxf(cm[q], __shfl_xor(cm[q], sh));
    }

    // merge into running max; rescale old sums/accumulators
    float p[H], sc[H];
    #pragma unroll
    for (int q=0;q<H;q++){
      float nm = fmaxf(m[q], cm[q]);
      sc[q] = __expf(m[q] - nm);          // 0 on first chunk (m=-inf)
      ssum[q] *= sc[q];
      m[q] = nm;
      p[q] = __expf(e[q] - nm);           // 0 for inactive lanes
    }
    float schh = sc[0];
    #pragma unroll
    for (int q=1;q<H;q++) schh = (hh==q) ? sc[q] : schh;
    a0 *= schh; a1 *= schh;

    // chunk sum per head
    float cs[H];
    #pragma unroll
    for (int q=0;q<H;q++) cs[q] = p[q];
    #pragma unroll
    for (int sh=1; sh<64; sh<<=1){
      #pragma unroll
      for (int q=0;q<H;q++) cs[q] += __shfl_xor(cs[q], sh);
    }
    #pragma unroll
    for (int q=0;q<H;q++) ssum[q] += cs[q];

    // stage weights + srcs for the accumulate loop (per-wave LDS slice)
    #pragma unroll
    for (int q=0;q<H;q++) s_p[wid][lane*H + q] = p[q];
    s_s[wid][lane] = sv;

    // accumulate: all gathers independent (srcs/weights known upfront)
    #pragma unroll 4
    for (int j=0;j<cl;j++){
      int s = s_s[wid][j];
      float w = s_p[wid][j*H + hh];
      const float2 hv = *reinterpret_cast<const float2*>(&h[(size_t)s*128 + c0]);
      a0 = fmaf(w, hv.x, a0);
      a1 = fmaf(w, hv.y, a1);
    }
  }

  float den = ssum[0];
  #pragma unroll
  for (int q=1;q<H;q++) den = (hh==q) ? ssum[q] : den;
  float inv = 1.f / den;
  out[(size_t)d*128 + c0] = elu_(a0*inv + bias[c0]);
  out[(size_t)d*128 + c1] = elu_(a1*inv + bias[c1]);
}

// ---------------- global mean pool (batch is sorted) ----------------
__global__ __launch_bounds__(256) void kpool(const float* __restrict__ act,
    const int* __restrict__ batch, int n, float* __restrict__ pool)
{
  __shared__ int sb[2];
  __shared__ float part[128];
  int g = blockIdx.x, tid = threadIdx.x;
  if (tid == 0){
    int lo=0, hi=n;
    while (lo<hi){ int mid=(lo+hi)>>1; if (batch[mid] < g) lo=mid+1; else hi=mid; }
    sb[0]=lo;
    int lo2=lo, hi2=n;
    while (lo2<hi2){ int mid=(lo2+hi2)>>1; if (batch[mid] < g+1) lo2=mid+1; else hi2=mid; }
    sb[1]=lo2;
  }
  __syncthreads();
  int lo=sb[0], hi=sb[1];
  int c = tid & 127, half = tid >> 7;
  float acc = 0.f;
  for (int i=lo+half; i<hi; i+=2) acc += act[(size_t)i*128 + c];
  if (half == 0) part[c] = acc;
  __syncthreads();
  if (half == 1) part[c] += acc;
  __syncthreads();
  if (half == 0){
    float cnt = (float)(hi-lo);
    pool[(size_t)g*128 + c] = part[c] / fmaxf(cnt, 1.f);
  }
}

// ---------------- classifier head ----------------
__global__ __launch_bounds__(64) void kclassify(const float* __restrict__ pool,
    const float* __restrict__ Wc1, const float* __restrict__ bc1,
    const float* __restrict__ Wc2, const float* __restrict__ bc2,
    float* __restrict__ logits)
{
  int g = blockIdx.x, j = threadIdx.x;
  const float* hp = pool + (size_t)g*128;
  float t = bc1[j];
  #pragma unroll 8
  for (int c=0;c<128;c++) t = fmaf(hp[c], Wc1[c*64+j], t);
  t = fmaxf(t, 0.f) * Wc2[j];
  for (int m=1;m<64;m<<=1) t += __shfl_xor(t, m);
  if (j==0) logits[g] = t + bc2[0];
}

extern "C" void kernel_launch(void* const* d_in, const int* in_sizes, int n_in,
                              void* d_out, int out_size, void* d_ws, size_t ws_size,
                              hipStream_t stream)
{
  const int*   x_lex = (const int*)d_in[0];
  const int*   ei    = (const int*)d_in[1];
  const int*   batch = (const int*)d_in[2];
  const float* emb   = (const float*)d_in[3];
  const float* W1    = (const float*)d_in[4];
  const float* a1s   = (const float*)d_in[5];
  const float* a1d   = (const float*)d_in[6];
  const float* b1    = (const float*)d_in[7];
  const float* W2    = (const float*)d_in[8];
  const float* a2s   = (const float*)d_in[9];
  const float* a2d   = (const float*)d_in[10];
  const float* b2    = (const float*)d_in[11];
  const float* Wc1   = (const float*)d_in[12];
  const float* bc1   = (const float*)d_in[13];
  const float* Wc2   = (const float*)d_in[14];
  const float* bc2   = (const float*)d_in[15];

  int N = in_sizes[0];
  int E = in_sizes[1] / 2;
  int Etot = E + N;
  const int G = 256;

  char* p = (char*)d_ws;
  float* hbuf = (float*)p;            p += (size_t)N*128*4;
  float* act  = (float*)p;            p += (size_t)N*128*4;
  float* als  = (float*)p;            p += (size_t)N*4*4;
  float* ald  = (float*)p;            p += (size_t)N*4*4;
  int* deg    = (int*)p;              p += (size_t)N*4;
  int* off    = (int*)p;              p += (size_t)(N+1)*4;
  int* cursor = (int*)p;              p += (size_t)N*4;
  int* bsum   = (int*)p;              p += 256*4;
  int* bpre   = (int*)p;              p += 256*4;
  int* srcs   = (int*)p;              /* Etot ints */

  // ---- CSR build (shared by both GAT layers) ----
  hipMemsetAsync(deg, 0, (size_t)N*4, stream);
  int eb = (Etot + 255)/256;
  khist<<<eb,256,0,stream>>>(ei, E, Etot, deg);
  int nb = (N + SCAN_CHUNK-1)/SCAN_CHUNK;
  kscan1<<<nb,256,0,stream>>>(deg, N, bsum);
  kscan2<<<1,64,0,stream>>>(bsum, bpre, nb, off, N, Etot);
  kscan3<<<nb,256,0,stream>>>(deg, N, bpre, off, cursor);
  kscatter<<<eb,256,0,stream>>>(ei, E, Etot, cursor, srcs);

  // ---- layer 1: h = emb[x_lex] @ W1, 4 heads ----
  int gb = (N + 31)/32;
  gemm_al<4,true ><<<gb,256,0,stream>>>(emb, x_lex, W1, a1s, a1d, hbuf, als, ald, N);
  aggr<4><<<(N+3)/4,256,0,stream>>>(hbuf, als, ald, srcs, off, b1, act, N);

  // ---- layer 2: h2 = act @ W2, 1 head ----
  gemm_al<1,false><<<gb,256,0,stream>>>(act, nullptr, W2, a2s, a2d, hbuf, als, ald, N);
  aggr<1><<<(N+3)/4,256,0,stream>>>(hbuf, als, ald, srcs, off, b2, act, N);

  // ---- pool + classifier ----
  float* out = (float*)d_out;
  kpool<<<G,256,0,stream>>>(act, batch, N, out + G);
  kclassify<<<G,64,0,stream>>>(out + G, Wc1, bc1, Wc2, bc2, out);
}

// Round 6
// 678.449 us; speedup vs baseline: 1.4145x; 1.0300x over previous
//
#include <hip/hip_runtime.h>
#include <hip/hip_bf16.h>
#include <math.h>

#define SCAN_CHUNK 4096

__device__ __forceinline__ float lrelu(float x){ return x < 0.f ? 0.2f*x : x; }
__device__ __forceinline__ float elu_(float x){ return x > 0.f ? x : expm1f(x); }

// ---------------- CSR build ----------------
__global__ void khist(const int* __restrict__ ei, int E, int Etot, int* __restrict__ deg){
  int i = blockIdx.x*blockDim.x + threadIdx.x;
  if (i >= Etot) return;
  int dst = (i < E) ? ei[E + i] : (i - E);
  atomicAdd(&deg[dst], 1);
}

__global__ void kscan1(const int* __restrict__ deg, int n, int* __restrict__ bsum){
  __shared__ int wsum[4];
  int blk = blockIdx.x, tid = threadIdx.x;
  int base = blk*SCAN_CHUNK + tid*16;
  int s = 0;
  #pragma unroll
  for (int j=0;j<16;j++){ int idx = base+j; if (idx < n) s += deg[idx]; }
  for (int m=1;m<64;m<<=1) s += __shfl_xor(s, m);
  if ((tid&63)==0) wsum[tid>>6] = s;
  __syncthreads();
  if (tid==0) bsum[blk] = wsum[0]+wsum[1]+wsum[2]+wsum[3];
}

__global__ void kscan2(const int* __restrict__ bsum, int* __restrict__ bpre, int nb,
                       int* __restrict__ off, int n, int Etot){
  if (threadIdx.x==0 && blockIdx.x==0){
    int run = 0;
    for (int i=0;i<nb;i++){ bpre[i] = run; run += bsum[i]; }
    off[n] = Etot;
  }
}

__global__ void kscan3(const int* __restrict__ deg, int n, const int* __restrict__ bpre,
                       int* __restrict__ off, int* __restrict__ cursor){
  __shared__ int wtot[4];
  int blk = blockIdx.x, tid = threadIdx.x, lane = tid & 63, w = tid >> 6;
  int base = blk*SCAN_CHUNK + tid*16;
  int v[16]; int s = 0;
  #pragma unroll
  for (int j=0;j<16;j++){ int idx = base+j; v[j] = (idx<n) ? deg[idx] : 0; s += v[j]; }
  int x = s;
  for (int d=1; d<64; d<<=1){ int y = __shfl_up(x, d); if (lane >= (int)d) x += y; }
  int texcl = x - s;
  if (lane == 63) wtot[w] = x;
  __syncthreads();
  int wprefix = 0;
  for (int i=0;i<w;i++) wprefix += wtot[i];
  int run = bpre[blk] + wprefix + texcl;
  #pragma unroll
  for (int j=0;j<16;j++){
    int idx = base+j;
    if (idx < n){ off[idx] = run; cursor[idx] = run; run += v[j]; }
  }
}

__global__ void kscatter(const int* __restrict__ ei, int E, int Etot,
                         int* __restrict__ cursor, int* __restrict__ srcs){
  int i = blockIdx.x*blockDim.x + threadIdx.x;
  if (i >= Etot) return;
  int s, d;
  if (i < E){ s = ei[i]; d = ei[E+i]; } else { s = i-E; d = i-E; }
  int p = atomicAdd(&cursor[d], 1);
  srcs[p] = s;
}

// ---------------- fused (gather) + GEMM(128x128) + attention-logit reductions ----------------
// 256 threads = 8 row-groups x 32 col-groups; each thread owns a 4x4 tile.
// X staged TRANSPOSED in LDS (xs[k][row], pad 36 keeps 16B alignment + banks),
// so the inner loop is 2x ds_read_b128 per 16 FMA -> FMA-bound.
template<int H, bool GATHER>
__global__ __launch_bounds__(256) void gemm_al(
    const float* __restrict__ X, const int* __restrict__ idx,
    const float* __restrict__ W, const float* __restrict__ asrc,
    const float* __restrict__ adst, float* __restrict__ Hout,
    float* __restrict__ als, float* __restrict__ ald, int n)
{
  __shared__ float xs[128][36];     // [k][row] transposed, padded
  __shared__ float wch[32][128];    // [k within chunk][col]
  int tid = threadIdx.x;
  int tr = tid >> 5, tc = tid & 31;
  int r4 = tr*4, c4 = tc*4;
  int row0 = blockIdx.x * 32;

  // stage X transposed: 32 rows x 128 cols = 1024 float4, 4 per thread
  #pragma unroll
  for (int j=0;j<4;j++){
    int e = tid + j*256;
    int r = e >> 5, cq = e & 31;
    int gr = row0 + r;
    float4 v = make_float4(0.f,0.f,0.f,0.f);
    if (gr < n){
      int srow = GATHER ? idx[gr] : gr;
      v = *reinterpret_cast<const float4*>(&X[(size_t)srow*128 + cq*4]);
    }
    xs[cq*4+0][r] = v.x;
    xs[cq*4+1][r] = v.y;
    xs[cq*4+2][r] = v.z;
    xs[cq*4+3][r] = v.w;
  }

  float acc[4][4];
  #pragma unroll
  for (int r=0;r<4;r++)
    #pragma unroll
    for (int i=0;i<4;i++) acc[r][i] = 0.f;

  for (int kc=0;kc<4;kc++){
    __syncthreads();
    #pragma unroll
    for (int j=0;j<4;j++){
      int e = tid + j*256;
      int r = e>>5, cq = e&31;
      *reinterpret_cast<float4*>(&wch[r][cq*4]) =
        *reinterpret_cast<const float4*>(&W[(size_t)(kc*32+r)*128 + cq*4]);
    }
    __syncthreads();
    #pragma unroll
    for (int kk=0;kk<32;kk++){
      const float4 xv = *reinterpret_cast<const float4*>(&xs[kc*32+kk][r4]);
      const float4 wv = *reinterpret_cast<const float4*>(&wch[kk][c4]);
      acc[0][0] = fmaf(xv.x, wv.x, acc[0][0]);
      acc[0][1] = fmaf(xv.x, wv.y, acc[0][1]);
      acc[0][2] = fmaf(xv.x, wv.z, acc[0][2]);
      acc[0][3] = fmaf(xv.x, wv.w, acc[0][3]);
      acc[1][0] = fmaf(xv.y, wv.x, acc[1][0]);
      acc[1][1] = fmaf(xv.y, wv.y, acc[1][1]);
      acc[1][2] = fmaf(xv.y, wv.z, acc[1][2]);
      acc[1][3] = fmaf(xv.y, wv.w, acc[1][3]);
      acc[2][0] = fmaf(xv.z, wv.x, acc[2][0]);
      acc[2][1] = fmaf(xv.z, wv.y, acc[2][1]);
      acc[2][2] = fmaf(xv.z, wv.z, acc[2][2]);
      acc[2][3] = fmaf(xv.z, wv.w, acc[2][3]);
      acc[3][0] = fmaf(xv.w, wv.x, acc[3][0]);
      acc[3][1] = fmaf(xv.w, wv.y, acc[3][1]);
      acc[3][2] = fmaf(xv.w, wv.z, acc[3][2]);
      acc[3][3] = fmaf(xv.w, wv.w, acc[3][3]);
    }
  }

  // epilogue: store H rows + attention-logit reductions
  const float4 asv = *reinterpret_cast<const float4*>(&asrc[c4]);
  const float4 adv = *reinterpret_cast<const float4*>(&adst[c4]);
  const int GT = 32 / H;            // tc-threads per head (H=4 -> 8, H=1 -> 32)
  int hh = tc / GT;

  #pragma unroll
  for (int r=0;r<4;r++){
    int gr = row0 + r4 + r;
    if (gr < n){
      *reinterpret_cast<float4*>(&Hout[(size_t)gr*128 + c4]) =
        make_float4(acc[r][0], acc[r][1], acc[r][2], acc[r][3]);
    }
    float ps = acc[r][0]*asv.x + acc[r][1]*asv.y + acc[r][2]*asv.z + acc[r][3]*asv.w;
    float pd = acc[r][0]*adv.x + acc[r][1]*adv.y + acc[r][2]*adv.z + acc[r][3]*adv.w;
    #pragma unroll
    for (int m=1;m<GT;m<<=1){ ps += __shfl_xor(ps,m); pd += __shfl_xor(pd,m); }
    if ((tc & (GT-1)) == 0 && gr < n){
      als[(size_t)gr*H + hh] = ps;
      ald[(size_t)gr*H + hh] = pd;
    }
  }
}

// ---------------- per-dst segment softmax + weighted aggregation ----------------
// One 64-lane wave per destination node. Wave-cooperative: lanes act as
// edges for the softmax (coalesced srcs load + shfl butterflies), then as
// channels for the accumulate (weights staged in LDS; h-row gathers are
// independent -> deep pipelining). Online-softmax chunking handles deg>64.
template<int H>
__global__ __launch_bounds__(256) void aggr(
    const float* __restrict__ h, const float* __restrict__ als,
    const float* __restrict__ ald, const int* __restrict__ srcs,
    const int* __restrict__ off, const float* __restrict__ bias,
    float* __restrict__ out, int n)
{
  __shared__ float s_p[4][64*H];
  __shared__ int   s_s[4][64];
  int tid = threadIdx.x;
  int wid = tid >> 6, lane = tid & 63;
  int d = blockIdx.x*4 + wid;
  if (d >= n) return;
  int c0 = 2*lane, c1 = c0+1;
  const int hh = (H==1) ? 0 : (lane >> 4);   // head owning channels c0,c1

  int s0 = off[d], s1 = off[d+1];

  float adv[H];
  #pragma unroll
  for (int q=0;q<H;q++) adv[q] = ald[(size_t)d*H + q];

  float m[H], ssum[H];
  #pragma unroll
  for (int q=0;q<H;q++){ m[q] = -INFINITY; ssum[q] = 0.f; }
  float a0 = 0.f, a1 = 0.f;

  for (int base = s0; base < s1; base += 64){
    int cl = s1 - base; if (cl > 64) cl = 64;

    int sv = 0;
    float e[H];
    if (lane < cl){
      sv = srcs[base + lane];
      #pragma unroll
      for (int q=0;q<H;q++) e[q] = lrelu(als[(size_t)sv*H + q] + adv[q]);
    } else {
      #pragma unroll
      for (int q=0;q<H;q++) e[q] = -INFINITY;
    }

    // chunk max per head (all 64 lanes participate; inactive = -INF)
    float cm[H];
    #pragma unroll
    for (int q=0;q<H;q++) cm[q] = e[q];
    #pragma unroll
    for (int sh=1; sh<64; sh<<=1){
      #pragma unroll
      for (int q=0;q<H;q++) cm[q] = fmaxf(cm[q], __shfl_xor(cm[q], sh));
    }

    // merge into running max; rescale old sums/accumulators
    float p[H], sc[H];
    #pragma unroll
    for (int q=0;q<H;q++){
      float nm = fmaxf(m[q], cm[q]);
      sc[q] = __expf(m[q] - nm);          // 0 on first chunk (m=-inf)
      ssum[q] *= sc[q];
      m[q] = nm;
      p[q] = __expf(e[q] - nm);           // 0 for inactive lanes
    }
    float schh = sc[0];
    #pragma unroll
    for (int q=1;q<H;q++) schh = (hh==q) ? sc[q] : schh;
    a0 *= schh; a1 *= schh;

    // chunk sum per head
    float cs[H];
    #pragma unroll
    for (int q=0;q<H;q++) cs[q] = p[q];
    #pragma unroll
    for (int sh=1; sh<64; sh<<=1){
      #pragma unroll
      for (int q=0;q<H;q++) cs[q] += __shfl_xor(cs[q], sh);
    }
    #pragma unroll
    for (int q=0;q<H;q++) ssum[q] += cs[q];

    // stage weights + srcs for the accumulate loop (per-wave LDS slice)
    #pragma unroll
    for (int q=0;q<H;q++) s_p[wid][lane*H + q] = p[q];
    s_s[wid][lane] = sv;

    // accumulate: all gathers independent (srcs/weights known upfront)
    #pragma unroll 4
    for (int j=0;j<cl;j++){
      int s = s_s[wid][j];
      float w = s_p[wid][j*H + hh];
      const float2 hv = *reinterpret_cast<const float2*>(&h[(size_t)s*128 + c0]);
      a0 = fmaf(w, hv.x, a0);
      a1 = fmaf(w, hv.y, a1);
    }
  }

  float den = ssum[0];
  #pragma unroll
  for (int q=1;q<H;q++) den = (hh==q) ? ssum[q] : den;
  float inv = 1.f / den;
  out[(size_t)d*128 + c0] = elu_(a0*inv + bias[c0]);
  out[(size_t)d*128 + c1] = elu_(a1*inv + bias[c1]);
}

// ---------------- global mean pool (batch is sorted) ----------------
__global__ __launch_bounds__(256) void kpool(const float* __restrict__ act,
    const int* __restrict__ batch, int n, float* __restrict__ pool)
{
  __shared__ int sb[2];
  __shared__ float part[128];
  int g = blockIdx.x, tid = threadIdx.x;
  if (tid == 0){
    int lo=0, hi=n;
    while (lo<hi){ int mid=(lo+hi)>>1; if (batch[mid] < g) lo=mid+1; else hi=mid; }
    sb[0]=lo;
    int lo2=lo, hi2=n;
    while (lo2<hi2){ int mid=(lo2+hi2)>>1; if (batch[mid] < g+1) lo2=mid+1; else hi2=mid; }
    sb[1]=lo2;
  }
  __syncthreads();
  int lo=sb[0], hi=sb[1];
  int c = tid & 127, half = tid >> 7;
  float acc = 0.f;
  for (int i=lo+half; i<hi; i+=2) acc += act[(size_t)i*128 + c];
  if (half == 0) part[c] = acc;
  __syncthreads();
  if (half == 1) part[c] += acc;
  __syncthreads();
  if (half == 0){
    float cnt = (float)(hi-lo);
    pool[(size_t)g*128 + c] = part[c] / fmaxf(cnt, 1.f);
  }
}

// ---------------- classifier head ----------------
__global__ __launch_bounds__(64) void kclassify(const float* __restrict__ pool,
    const float* __restrict__ Wc1, const float* __restrict__ bc1,
    const float* __restrict__ Wc2, const float* __restrict__ bc2,
    float* __restrict__ logits)
{
  int g = blockIdx.x, j = threadIdx.x;
  const float* hp = pool + (size_t)g*128;
  float t = bc1[j];
  #pragma unroll 8
  for (int c=0;c<128;c++) t = fmaf(hp[c], Wc1[c*64+j], t);
  t = fmaxf(t, 0.f) * Wc2[j];
  for (int m=1;m<64;m<<=1) t += __shfl_xor(t, m);
  if (j==0) logits[g] = t + bc2[0];
}

extern "C" void kernel_launch(void* const* d_in, const int* in_sizes, int n_in,
                              void* d_out, int out_size, void* d_ws, size_t ws_size,
                              hipStream_t stream)
{
  const int*   x_lex = (const int*)d_in[0];
  const int*   ei    = (const int*)d_in[1];
  const int*   batch = (const int*)d_in[2];
  const float* emb   = (const float*)d_in[3];
  const float* W1    = (const float*)d_in[4];
  const float* a1s   = (const float*)d_in[5];
  const float* a1d   = (const float*)d_in[6];
  const float* b1    = (const float*)d_in[7];
  const float* W2    = (const float*)d_in[8];
  const float* a2s   = (const float*)d_in[9];
  const float* a2d   = (const float*)d_in[10];
  const float* b2    = (const float*)d_in[11];
  const float* Wc1   = (const float*)d_in[12];
  const float* bc1   = (const float*)d_in[13];
  const float* Wc2   = (const float*)d_in[14];
  const float* bc2   = (const float*)d_in[15];

  int N = in_sizes[0];
  int E = in_sizes[1] / 2;
  int Etot = E + N;
  const int G = 256;

  char* p = (char*)d_ws;
  float* hbuf = (float*)p;            p += (size_t)N*128*4;
  float* act  = (float*)p;            p += (size_t)N*128*4;
  float* als  = (float*)p;            p += (size_t)N*4*4;
  float* ald  = (float*)p;            p += (size_t)N*4*4;
  int* deg    = (int*)p;              p += (size_t)N*4;
  int* off    = (int*)p;              p += (size_t)(N+1)*4;
  int* cursor = (int*)p;              p += (size_t)N*4;
  int* bsum   = (int*)p;              p += 256*4;
  int* bpre   = (int*)p;              p += 256*4;
  int* srcs   = (int*)p;              /* Etot ints */

  // ---- CSR build (shared by both GAT layers) ----
  hipMemsetAsync(deg, 0, (size_t)N*4, stream);
  int eb = (Etot + 255)/256;
  khist<<<eb,256,0,stream>>>(ei, E, Etot, deg);
  int nb = (N + SCAN_CHUNK-1)/SCAN_CHUNK;
  kscan1<<<nb,256,0,stream>>>(deg, N, bsum);
  kscan2<<<1,64,0,stream>>>(bsum, bpre, nb, off, N, Etot);
  kscan3<<<nb,256,0,stream>>>(deg, N, bpre, off, cursor);
  kscatter<<<eb,256,0,stream>>>(ei, E, Etot, cursor, srcs);

  // ---- layer 1: h = emb[x_lex] @ W1, 4 heads ----
  int gb = (N + 31)/32;
  gemm_al<4,true ><<<gb,256,0,stream>>>(emb, x_lex, W1, a1s, a1d, hbuf, als, ald, N);
  aggr<4><<<(N+3)/4,256,0,stream>>>(hbuf, als, ald, srcs, off, b1, act, N);

  // ---- layer 2: h2 = act @ W2, 1 head ----
  gemm_al<1,false><<<gb,256,0,stream>>>(act, nullptr, W2, a2s, a2d, hbuf, als, ald, N);
  aggr<1><<<(N+3)/4,256,0,stream>>>(hbuf, als, ald, srcs, off, b2, act, N);

  // ---- pool + classifier ----
  float* out = (float*)d_out;
  kpool<<<G,256,0,stream>>>(act, batch, N, out + G);
  kclassify<<<G,64,0,stream>>>(out + G, Wc1, bc1, Wc2, bc2, out);
}

// Round 7
// 675.271 us; speedup vs baseline: 1.4212x; 1.0047x over previous
//
#include <hip/hip_runtime.h>
#include <hip/hip_bf16.h>
#include <math.h>

#define SCAN_CHUNK 4096

__device__ __forceinline__ float lrelu(float x){ return x < 0.f ? 0.2f*x : x; }
__device__ __forceinline__ float elu_(float x){ return x > 0.f ? x : expm1f(x); }

// ---------------- CSR build ----------------
__global__ void khist(const int* __restrict__ ei, int E, int Etot, int* __restrict__ deg){
  int i = blockIdx.x*blockDim.x + threadIdx.x;
  if (i >= Etot) return;
  int dst = (i < E) ? ei[E + i] : (i - E);
  atomicAdd(&deg[dst], 1);
}

__global__ void kscan1(const int* __restrict__ deg, int n, int* __restrict__ bsum){
  __shared__ int wsum[4];
  int blk = blockIdx.x, tid = threadIdx.x;
  int base = blk*SCAN_CHUNK + tid*16;
  int s = 0;
  #pragma unroll
  for (int j=0;j<16;j++){ int idx = base+j; if (idx < n) s += deg[idx]; }
  for (int m=1;m<64;m<<=1) s += __shfl_xor(s, m);
  if ((tid&63)==0) wsum[tid>>6] = s;
  __syncthreads();
  if (tid==0) bsum[blk] = wsum[0]+wsum[1]+wsum[2]+wsum[3];
}

__global__ void kscan2(const int* __restrict__ bsum, int* __restrict__ bpre, int nb,
                       int* __restrict__ off, int n, int Etot){
  if (threadIdx.x==0 && blockIdx.x==0){
    int run = 0;
    for (int i=0;i<nb;i++){ bpre[i] = run; run += bsum[i]; }
    off[n] = Etot;
  }
}

__global__ void kscan3(const int* __restrict__ deg, int n, const int* __restrict__ bpre,
                       int* __restrict__ off, int* __restrict__ cursor){
  __shared__ int wtot[4];
  int blk = blockIdx.x, tid = threadIdx.x, lane = tid & 63, w = tid >> 6;
  int base = blk*SCAN_CHUNK + tid*16;
  int v[16]; int s = 0;
  #pragma unroll
  for (int j=0;j<16;j++){ int idx = base+j; v[j] = (idx<n) ? deg[idx] : 0; s += v[j]; }
  int x = s;
  for (int d=1; d<64; d<<=1){ int y = __shfl_up(x, d); if (lane >= (int)d) x += y; }
  int texcl = x - s;
  if (lane == 63) wtot[w] = x;
  __syncthreads();
  int wprefix = 0;
  for (int i=0;i<w;i++) wprefix += wtot[i];
  int run = bpre[blk] + wprefix + texcl;
  #pragma unroll
  for (int j=0;j<16;j++){
    int idx = base+j;
    if (idx < n){ off[idx] = run; cursor[idx] = run; run += v[j]; }
  }
}

__global__ void kscatter(const int* __restrict__ ei, int E, int Etot,
                         int* __restrict__ cursor, int* __restrict__ srcs){
  int i = blockIdx.x*blockDim.x + threadIdx.x;
  if (i >= Etot) return;
  int s, d;
  if (i < E){ s = ei[i]; d = ei[E+i]; } else { s = i-E; d = i-E; }
  int p = atomicAdd(&cursor[d], 1);
  srcs[p] = s;
}

// ---------------- fused (gather) + GEMM(128x128) + attention-logit reductions ----------------
// 64-row tile, 256 threads = 8 row-groups x 32 col-groups; each thread owns 8x4.
// X transposed in LDS; per kk: 3x ds_read_b128 per 32 FMA -> VALU-bound.
template<int H, bool GATHER>
__global__ __launch_bounds__(256) void gemm_al(
    const float* __restrict__ X, const int* __restrict__ idx,
    const float* __restrict__ W, const float* __restrict__ asrc,
    const float* __restrict__ adst, float* __restrict__ Hout,
    float* __restrict__ als, float* __restrict__ ald, int n)
{
  __shared__ float xs[128][68];     // [k][row] transposed, padded (68: b128-aligned, bank-spread)
  __shared__ float wch[32][128];    // [k within chunk][col]
  int tid = threadIdx.x;
  int tr = tid >> 5, tc = tid & 31;
  int r8 = tr*8, c4 = tc*4;
  int row0 = blockIdx.x * 64;

  // stage X transposed: 64 rows x 32 float4-cols = 2048 float4, 8 per thread
  #pragma unroll
  for (int j=0;j<8;j++){
    int e = tid + j*256;
    int r = e >> 5, cq = e & 31;
    int gr = row0 + r;
    float4 v = make_float4(0.f,0.f,0.f,0.f);
    if (gr < n){
      int srow = GATHER ? idx[gr] : gr;
      v = *reinterpret_cast<const float4*>(&X[(size_t)srow*128 + cq*4]);
    }
    xs[cq*4+0][r] = v.x;
    xs[cq*4+1][r] = v.y;
    xs[cq*4+2][r] = v.z;
    xs[cq*4+3][r] = v.w;
  }

  float acc[8][4];
  #pragma unroll
  for (int r=0;r<8;r++)
    #pragma unroll
    for (int i=0;i<4;i++) acc[r][i] = 0.f;

  for (int kc=0;kc<4;kc++){
    __syncthreads();
    #pragma unroll
    for (int j=0;j<4;j++){
      int e = tid + j*256;
      int r = e>>5, cq = e&31;
      *reinterpret_cast<float4*>(&wch[r][cq*4]) =
        *reinterpret_cast<const float4*>(&W[(size_t)(kc*32+r)*128 + cq*4]);
    }
    __syncthreads();
    #pragma unroll
    for (int kk=0;kk<32;kk++){
      int k = kc*32+kk;
      const float4 x0 = *reinterpret_cast<const float4*>(&xs[k][r8]);
      const float4 x1 = *reinterpret_cast<const float4*>(&xs[k][r8+4]);
      const float4 wv = *reinterpret_cast<const float4*>(&wch[kk][c4]);
      acc[0][0]=fmaf(x0.x,wv.x,acc[0][0]); acc[0][1]=fmaf(x0.x,wv.y,acc[0][1]);
      acc[0][2]=fmaf(x0.x,wv.z,acc[0][2]); acc[0][3]=fmaf(x0.x,wv.w,acc[0][3]);
      acc[1][0]=fmaf(x0.y,wv.x,acc[1][0]); acc[1][1]=fmaf(x0.y,wv.y,acc[1][1]);
      acc[1][2]=fmaf(x0.y,wv.z,acc[1][2]); acc[1][3]=fmaf(x0.y,wv.w,acc[1][3]);
      acc[2][0]=fmaf(x0.z,wv.x,acc[2][0]); acc[2][1]=fmaf(x0.z,wv.y,acc[2][1]);
      acc[2][2]=fmaf(x0.z,wv.z,acc[2][2]); acc[2][3]=fmaf(x0.z,wv.w,acc[2][3]);
      acc[3][0]=fmaf(x0.w,wv.x,acc[3][0]); acc[3][1]=fmaf(x0.w,wv.y,acc[3][1]);
      acc[3][2]=fmaf(x0.w,wv.z,acc[3][2]); acc[3][3]=fmaf(x0.w,wv.w,acc[3][3]);
      acc[4][0]=fmaf(x1.x,wv.x,acc[4][0]); acc[4][1]=fmaf(x1.x,wv.y,acc[4][1]);
      acc[4][2]=fmaf(x1.x,wv.z,acc[4][2]); acc[4][3]=fmaf(x1.x,wv.w,acc[4][3]);
      acc[5][0]=fmaf(x1.y,wv.x,acc[5][0]); acc[5][1]=fmaf(x1.y,wv.y,acc[5][1]);
      acc[5][2]=fmaf(x1.y,wv.z,acc[5][2]); acc[5][3]=fmaf(x1.y,wv.w,acc[5][3]);
      acc[6][0]=fmaf(x1.z,wv.x,acc[6][0]); acc[6][1]=fmaf(x1.z,wv.y,acc[6][1]);
      acc[6][2]=fmaf(x1.z,wv.z,acc[6][2]); acc[6][3]=fmaf(x1.z,wv.w,acc[6][3]);
      acc[7][0]=fmaf(x1.w,wv.x,acc[7][0]); acc[7][1]=fmaf(x1.w,wv.y,acc[7][1]);
      acc[7][2]=fmaf(x1.w,wv.z,acc[7][2]); acc[7][3]=fmaf(x1.w,wv.w,acc[7][3]);
    }
  }

  // epilogue: store H rows + attention-logit reductions
  const float4 asv = *reinterpret_cast<const float4*>(&asrc[c4]);
  const float4 adv = *reinterpret_cast<const float4*>(&adst[c4]);
  const int GT = 32 / H;            // tc-threads per head (H=4 -> 8, H=1 -> 32)
  int hh = tc / GT;

  #pragma unroll
  for (int r=0;r<8;r++){
    int gr = row0 + r8 + r;
    if (gr < n){
      *reinterpret_cast<float4*>(&Hout[(size_t)gr*128 + c4]) =
        make_float4(acc[r][0], acc[r][1], acc[r][2], acc[r][3]);
    }
    float ps = acc[r][0]*asv.x + acc[r][1]*asv.y + acc[r][2]*asv.z + acc[r][3]*asv.w;
    float pd = acc[r][0]*adv.x + acc[r][1]*adv.y + acc[r][2]*adv.z + acc[r][3]*adv.w;
    #pragma unroll
    for (int m=1;m<GT;m<<=1){ ps += __shfl_xor(ps,m); pd += __shfl_xor(pd,m); }
    if ((tc & (GT-1)) == 0 && gr < n){
      als[(size_t)gr*H + hh] = ps;
      ald[(size_t)gr*H + hh] = pd;
    }
  }
}

// ---------------- per-dst segment softmax + weighted aggregation ----------------
// One wave per dst. Softmax phase: lanes = edges (coalesced srcs load + shfl
// butterflies). Accumulate phase: float4 x 2-edges-per-iter — lanes 0-31 even
// edges / 32-63 odd edges, 4 channels per lane, one shfl_xor(32) combine.
template<int H>
__global__ __launch_bounds__(256) void aggr(
    const float* __restrict__ h, const float* __restrict__ als,
    const float* __restrict__ ald, const int* __restrict__ srcs,
    const int* __restrict__ off, const float* __restrict__ bias,
    float* __restrict__ out, int n)
{
  __shared__ float s_p[4][64*H];
  __shared__ int   s_s[4][64];
  int tid = threadIdx.x;
  int wid = tid >> 6, lane = tid & 63;
  int d = blockIdx.x*4 + wid;
  if (d >= n) return;
  int half = lane >> 5, ch = lane & 31;
  int c4 = ch*4;
  const int hh = (H==1) ? 0 : (ch >> 3);   // head owning channels c4..c4+3

  int s0 = off[d], s1 = off[d+1];

  float adv[H];
  #pragma unroll
  for (int q=0;q<H;q++) adv[q] = ald[(size_t)d*H + q];

  float m[H], ssum[H];
  #pragma unroll
  for (int q=0;q<H;q++){ m[q] = -INFINITY; ssum[q] = 0.f; }
  float a0=0.f, a1=0.f, a2=0.f, a3=0.f;

  for (int base = s0; base < s1; base += 64){
    int cl = s1 - base; if (cl > 64) cl = 64;

    // --- softmax phase: lanes act as edges ---
    int sv = 0;
    float e[H];
    if (lane < cl){
      sv = srcs[base + lane];
      #pragma unroll
      for (int q=0;q<H;q++) e[q] = lrelu(als[(size_t)sv*H + q] + adv[q]);
    } else {
      #pragma unroll
      for (int q=0;q<H;q++) e[q] = -INFINITY;
    }

    float cm[H];
    #pragma unroll
    for (int q=0;q<H;q++) cm[q] = e[q];
    #pragma unroll
    for (int sh=1; sh<64; sh<<=1){
      #pragma unroll
      for (int q=0;q<H;q++) cm[q] = fmaxf(cm[q], __shfl_xor(cm[q], sh));
    }

    float p[H], sc[H];
    #pragma unroll
    for (int q=0;q<H;q++){
      float nm = fmaxf(m[q], cm[q]);
      sc[q] = __expf(m[q] - nm);
      ssum[q] *= sc[q];
      m[q] = nm;
      p[q] = __expf(e[q] - nm);
    }
    float schh = sc[0];
    #pragma unroll
    for (int q=1;q<H;q++) schh = (hh==q) ? sc[q] : schh;
    a0 *= schh; a1 *= schh; a2 *= schh; a3 *= schh;

    float cs[H];
    #pragma unroll
    for (int q=0;q<H;q++) cs[q] = p[q];
    #pragma unroll
    for (int sh=1; sh<64; sh<<=1){
      #pragma unroll
      for (int q=0;q<H;q++) cs[q] += __shfl_xor(cs[q], sh);
    }
    #pragma unroll
    for (int q=0;q<H;q++) ssum[q] += cs[q];

    #pragma unroll
    for (int q=0;q<H;q++) s_p[wid][lane*H + q] = p[q];
    s_s[wid][lane] = sv;

    // --- accumulate phase: 2 edges/iter, float4 rows ---
    for (int j = half; j < cl; j += 2){
      int s = s_s[wid][j];
      float w = s_p[wid][j*H + hh];
      const float4 hv = *reinterpret_cast<const float4*>(&h[(size_t)s*128 + c4]);
      a0 = fmaf(w, hv.x, a0);
      a1 = fmaf(w, hv.y, a1);
      a2 = fmaf(w, hv.z, a2);
      a3 = fmaf(w, hv.w, a3);
    }
  }

  // combine even/odd halves (same channels, same head -> same den)
  a0 += __shfl_xor(a0, 32);
  a1 += __shfl_xor(a1, 32);
  a2 += __shfl_xor(a2, 32);
  a3 += __shfl_xor(a3, 32);

  float den = ssum[0];
  #pragma unroll
  for (int q=1;q<H;q++) den = (hh==q) ? ssum[q] : den;
  float inv = 1.f / den;

  if (half == 0){
    const float4 bv = *reinterpret_cast<const float4*>(&bias[c4]);
    float4 o;
    o.x = elu_(a0*inv + bv.x);
    o.y = elu_(a1*inv + bv.y);
    o.z = elu_(a2*inv + bv.z);
    o.w = elu_(a3*inv + bv.w);
    *reinterpret_cast<float4*>(&out[(size_t)d*128 + c4]) = o;
  }
}

// ---------------- global mean pool (batch is sorted) ----------------
__global__ __launch_bounds__(256) void kpool(const float* __restrict__ act,
    const int* __restrict__ batch, int n, float* __restrict__ pool)
{
  __shared__ int sb[2];
  __shared__ float part[128];
  int g = blockIdx.x, tid = threadIdx.x;
  if (tid == 0){
    int lo=0, hi=n;
    while (lo<hi){ int mid=(lo+hi)>>1; if (batch[mid] < g) lo=mid+1; else hi=mid; }
    sb[0]=lo;
    int lo2=lo, hi2=n;
    while (lo2<hi2){ int mid=(lo2+hi2)>>1; if (batch[mid] < g+1) lo2=mid+1; else hi2=mid; }
    sb[1]=lo2;
  }
  __syncthreads();
  int lo=sb[0], hi=sb[1];
  int c = tid & 127, half = tid >> 7;
  float acc = 0.f;
  for (int i=lo+half; i<hi; i+=2) acc += act[(size_t)i*128 + c];
  if (half == 0) part[c] = acc;
  __syncthreads();
  if (half == 1) part[c] += acc;
  __syncthreads();
  if (half == 0){
    float cnt = (float)(hi-lo);
    pool[(size_t)g*128 + c] = part[c] / fmaxf(cnt, 1.f);
  }
}

// ---------------- classifier head ----------------
__global__ __launch_bounds__(64) void kclassify(const float* __restrict__ pool,
    const float* __restrict__ Wc1, const float* __restrict__ bc1,
    const float* __restrict__ Wc2, const float* __restrict__ bc2,
    float* __restrict__ logits)
{
  int g = blockIdx.x, j = threadIdx.x;
  const float* hp = pool + (size_t)g*128;
  float t = bc1[j];
  #pragma unroll 8
  for (int c=0;c<128;c++) t = fmaf(hp[c], Wc1[c*64+j], t);
  t = fmaxf(t, 0.f) * Wc2[j];
  for (int m=1;m<64;m<<=1) t += __shfl_xor(t, m);
  if (j==0) logits[g] = t + bc2[0];
}

extern "C" void kernel_launch(void* const* d_in, const int* in_sizes, int n_in,
                              void* d_out, int out_size, void* d_ws, size_t ws_size,
                              hipStream_t stream)
{
  const int*   x_lex = (const int*)d_in[0];
  const int*   ei    = (const int*)d_in[1];
  const int*   batch = (const int*)d_in[2];
  const float* emb   = (const float*)d_in[3];
  const float* W1    = (const float*)d_in[4];
  const float* a1s   = (const float*)d_in[5];
  const float* a1d   = (const float*)d_in[6];
  const float* b1    = (const float*)d_in[7];
  const float* W2    = (const float*)d_in[8];
  const float* a2s   = (const float*)d_in[9];
  const float* a2d   = (const float*)d_in[10];
  const float* b2    = (const float*)d_in[11];
  const float* Wc1   = (const float*)d_in[12];
  const float* bc1   = (const float*)d_in[13];
  const float* Wc2   = (const float*)d_in[14];
  const float* bc2   = (const float*)d_in[15];

  int N = in_sizes[0];
  int E = in_sizes[1] / 2;
  int Etot = E + N;
  const int G = 256;

  char* p = (char*)d_ws;
  float* hbuf = (float*)p;            p += (size_t)N*128*4;
  float* act  = (float*)p;            p += (size_t)N*128*4;
  float* als  = (float*)p;            p += (size_t)N*4*4;
  float* ald  = (float*)p;            p += (size_t)N*4*4;
  int* deg    = (int*)p;              p += (size_t)N*4;
  int* off    = (int*)p;              p += (size_t)(N+1)*4;
  int* cursor = (int*)p;              p += (size_t)N*4;
  int* bsum   = (int*)p;              p += 256*4;
  int* bpre   = (int*)p;              p += 256*4;
  int* srcs   = (int*)p;              /* Etot ints */

  // ---- CSR build (shared by both GAT layers) ----
  hipMemsetAsync(deg, 0, (size_t)N*4, stream);
  int eb = (Etot + 255)/256;
  khist<<<eb,256,0,stream>>>(ei, E, Etot, deg);
  int nb = (N + SCAN_CHUNK-1)/SCAN_CHUNK;
  kscan1<<<nb,256,0,stream>>>(deg, N, bsum);
  kscan2<<<1,64,0,stream>>>(bsum, bpre, nb, off, N, Etot);
  kscan3<<<nb,256,0,stream>>>(deg, N, bpre, off, cursor);
  kscatter<<<eb,256,0,stream>>>(ei, E, Etot, cursor, srcs);

  // ---- layer 1: h = emb[x_lex] @ W1, 4 heads ----
  int gb = (N + 63)/64;
  gemm_al<4,true ><<<gb,256,0,stream>>>(emb, x_lex, W1, a1s, a1d, hbuf, als, ald, N);
  aggr<4><<<(N+3)/4,256,0,stream>>>(hbuf, als, ald, srcs, off, b1, act, N);

  // ---- layer 2: h2 = act @ W2, 1 head ----
  gemm_al<1,false><<<gb,256,0,stream>>>(act, nullptr, W2, a2s, a2d, hbuf, als, ald, N);
  aggr<1><<<(N+3)/4,256,0,stream>>>(hbuf, als, ald, srcs, off, b2, act, N);

  // ---- pool + classifier ----
  float* out = (float*)d_out;
  kpool<<<G,256,0,stream>>>(act, batch, N, out + G);
  kclassify<<<G,64,0,stream>>>(out + G, Wc1, bc1, Wc2, bc2, out);
}

// Round 8
// 528.285 us; speedup vs baseline: 1.8166x; 1.2782x over previous
//
#include <hip/hip_runtime.h>
#include <hip/hip_bf16.h>
#include <math.h>

#define P_CHUNK 8192
#define NBKT 1024   // LDS bins; used buckets = ceil(N/128)

__device__ __forceinline__ float lrelu(float x){ return x < 0.f ? 0.2f*x : x; }
__device__ __forceinline__ float elu_(float x){ return x > 0.f ? x : expm1f(x); }

// ---------------- CSR build: bucket sort, LDS-privatized counting ----------------
// P1: per-block LDS histogram over buckets (dst>>7) -> global totals (163k atomics)
__global__ __launch_bounds__(256) void p1hist(const int* __restrict__ ei, int E, int Etot,
                                              int* __restrict__ totals){
  __shared__ int lh[NBKT];
  int tid = threadIdx.x;
  for (int t = tid; t < NBKT; t += 256) lh[t] = 0;
  __syncthreads();
  int base = blockIdx.x * P_CHUNK;
  for (int j = 0; j < P_CHUNK; j += 256){
    int i = base + j + tid;
    if (i < Etot){
      int dst = (i < E) ? ei[E + i] : (i - E);
      atomicAdd(&lh[dst >> 7], 1);
    }
  }
  __syncthreads();
  for (int t = tid; t < NBKT; t += 256){
    int v = lh[t];
    if (v) atomicAdd(&totals[t], v);
  }
}

// P2: single-block exclusive scan of bucket totals -> bbase, bcur; off[N]=Etot
__global__ __launch_bounds__(256) void p2scan(const int* __restrict__ totals,
                                              int* __restrict__ bbase, int* __restrict__ bcur,
                                              int Etot, int* __restrict__ off, int N){
  __shared__ int wsum[4];
  __shared__ int runsh;
  int tid = threadIdx.x, lane = tid & 63, w = tid >> 6;
  if (tid == 0) runsh = 0;
  __syncthreads();
  for (int c = 0; c < NBKT; c += 256){
    int v = totals[c + tid];
    int x = v;
    #pragma unroll
    for (int d = 1; d < 64; d <<= 1){ int y = __shfl_up(x, d); if (lane >= d) x += y; }
    if (lane == 63) wsum[w] = x;
    __syncthreads();
    int wpre = 0;
    for (int i = 0; i < w; i++) wpre += wsum[i];
    int run = runsh;
    int excl = run + wpre + x - v;
    bbase[c + tid] = excl;
    bcur[c + tid]  = excl;
    __syncthreads();
    if (tid == 0) runsh = run + wsum[0] + wsum[1] + wsum[2] + wsum[3];
    __syncthreads();
  }
  if (tid == 0){ bbase[NBKT] = Etot; off[N] = Etot; }
}

// P3: per-block LDS histogram -> slab reservation (1 global atomic per block-bucket),
// then LDS-rank scatter of (src,dst) into bucket slabs.
__global__ __launch_bounds__(256) void p3scatter(const int* __restrict__ ei, int E, int Etot,
                                                 int* __restrict__ bcur, int2* __restrict__ tmp){
  __shared__ int lh[NBKT];
  __shared__ int lbase[NBKT];
  int tid = threadIdx.x;
  for (int t = tid; t < NBKT; t += 256) lh[t] = 0;
  __syncthreads();
  int base = blockIdx.x * P_CHUNK;
  for (int j = 0; j < P_CHUNK; j += 256){
    int i = base + j + tid;
    if (i < Etot){
      int dst = (i < E) ? ei[E + i] : (i - E);
      atomicAdd(&lh[dst >> 7], 1);
    }
  }
  __syncthreads();
  for (int t = tid; t < NBKT; t += 256){
    int v = lh[t];
    lbase[t] = v ? atomicAdd(&bcur[t], v) : 0;
  }
  __syncthreads();
  for (int t = tid; t < NBKT; t += 256) lh[t] = 0;   // reuse as local cursor
  __syncthreads();
  for (int j = 0; j < P_CHUNK; j += 256){
    int i = base + j + tid;
    if (i < Etot){
      int s, d;
      if (i < E){ s = ei[i]; d = ei[E + i]; } else { s = i - E; d = i - E; }
      int b = d >> 7;
      int r = atomicAdd(&lh[b], 1);
      tmp[lbase[b] + r] = make_int2(s, d);
    }
  }
}

// P4: one block per bucket — exact per-dst offsets + src scatter (block-local writes)
__global__ __launch_bounds__(256) void p4local(const int2* __restrict__ tmp,
                                               const int* __restrict__ bbase,
                                               int* __restrict__ off, int* __restrict__ srcs, int N){
  __shared__ int cnt[128];
  __shared__ int offL[128];
  int b = blockIdx.x, tid = threadIdx.x;
  int e0 = bbase[b], e1 = bbase[b + 1];
  if (tid < 128) cnt[tid] = 0;
  __syncthreads();
  for (int j = e0 + tid; j < e1; j += 256)
    atomicAdd(&cnt[tmp[j].y & 127], 1);
  __syncthreads();
  if (tid < 64){
    int v0 = cnt[2*tid], v1 = cnt[2*tid + 1];
    int p = v0 + v1;
    int x = p;
    #pragma unroll
    for (int d = 1; d < 64; d <<= 1){ int y = __shfl_up(x, d); if (tid >= d) x += y; }
    int excl = x - p;
    offL[2*tid]     = excl;
    offL[2*tid + 1] = excl + v0;
  }
  __syncthreads();
  if (tid < 128){
    int gd = b*128 + tid;
    if (gd < N) off[gd] = e0 + offL[tid];
    cnt[tid] = 0;
  }
  __syncthreads();
  for (int j = e0 + tid; j < e1; j += 256){
    int2 e = tmp[j];
    int d = e.y & 127;
    int r = atomicAdd(&cnt[d], 1);
    srcs[e0 + offL[d] + r] = e.x;
  }
}

// ---------------- fused (gather) + GEMM(128x128) + attention-logit reductions ----------------
// 64-row tile, 256 threads = 8 row-groups x 32 col-groups; each thread owns 8x4.
template<int H, bool GATHER>
__global__ __launch_bounds__(256) void gemm_al(
    const float* __restrict__ X, const int* __restrict__ idx,
    const float* __restrict__ W, const float* __restrict__ asrc,
    const float* __restrict__ adst, float* __restrict__ Hout,
    float* __restrict__ als, float* __restrict__ ald, int n)
{
  __shared__ float xs[128][68];
  __shared__ float wch[32][128];
  int tid = threadIdx.x;
  int tr = tid >> 5, tc = tid & 31;
  int r8 = tr*8, c4 = tc*4;
  int row0 = blockIdx.x * 64;

  #pragma unroll
  for (int j=0;j<8;j++){
    int e = tid + j*256;
    int r = e >> 5, cq = e & 31;
    int gr = row0 + r;
    float4 v = make_float4(0.f,0.f,0.f,0.f);
    if (gr < n){
      int srow = GATHER ? idx[gr] : gr;
      v = *reinterpret_cast<const float4*>(&X[(size_t)srow*128 + cq*4]);
    }
    xs[cq*4+0][r] = v.x;
    xs[cq*4+1][r] = v.y;
    xs[cq*4+2][r] = v.z;
    xs[cq*4+3][r] = v.w;
  }

  float acc[8][4];
  #pragma unroll
  for (int r=0;r<8;r++)
    #pragma unroll
    for (int i=0;i<4;i++) acc[r][i] = 0.f;

  for (int kc=0;kc<4;kc++){
    __syncthreads();
    #pragma unroll
    for (int j=0;j<4;j++){
      int e = tid + j*256;
      int r = e>>5, cq = e&31;
      *reinterpret_cast<float4*>(&wch[r][cq*4]) =
        *reinterpret_cast<const float4*>(&W[(size_t)(kc*32+r)*128 + cq*4]);
    }
    __syncthreads();
    #pragma unroll
    for (int kk=0;kk<32;kk++){
      int k = kc*32+kk;
      const float4 x0 = *reinterpret_cast<const float4*>(&xs[k][r8]);
      const float4 x1 = *reinterpret_cast<const float4*>(&xs[k][r8+4]);
      const float4 wv = *reinterpret_cast<const float4*>(&wch[kk][c4]);
      acc[0][0]=fmaf(x0.x,wv.x,acc[0][0]); acc[0][1]=fmaf(x0.x,wv.y,acc[0][1]);
      acc[0][2]=fmaf(x0.x,wv.z,acc[0][2]); acc[0][3]=fmaf(x0.x,wv.w,acc[0][3]);
      acc[1][0]=fmaf(x0.y,wv.x,acc[1][0]); acc[1][1]=fmaf(x0.y,wv.y,acc[1][1]);
      acc[1][2]=fmaf(x0.y,wv.z,acc[1][2]); acc[1][3]=fmaf(x0.y,wv.w,acc[1][3]);
      acc[2][0]=fmaf(x0.z,wv.x,acc[2][0]); acc[2][1]=fmaf(x0.z,wv.y,acc[2][1]);
      acc[2][2]=fmaf(x0.z,wv.z,acc[2][2]); acc[2][3]=fmaf(x0.z,wv.w,acc[2][3]);
      acc[3][0]=fmaf(x0.w,wv.x,acc[3][0]); acc[3][1]=fmaf(x0.w,wv.y,acc[3][1]);
      acc[3][2]=fmaf(x0.w,wv.z,acc[3][2]); acc[3][3]=fmaf(x0.w,wv.w,acc[3][3]);
      acc[4][0]=fmaf(x1.x,wv.x,acc[4][0]); acc[4][1]=fmaf(x1.x,wv.y,acc[4][1]);
      acc[4][2]=fmaf(x1.x,wv.z,acc[4][2]); acc[4][3]=fmaf(x1.x,wv.w,acc[4][3]);
      acc[5][0]=fmaf(x1.y,wv.x,acc[5][0]); acc[5][1]=fmaf(x1.y,wv.y,acc[5][1]);
      acc[5][2]=fmaf(x1.y,wv.z,acc[5][2]); acc[5][3]=fmaf(x1.y,wv.w,acc[5][3]);
      acc[6][0]=fmaf(x1.z,wv.x,acc[6][0]); acc[6][1]=fmaf(x1.z,wv.y,acc[6][1]);
      acc[6][2]=fmaf(x1.z,wv.z,acc[6][2]); acc[6][3]=fmaf(x1.z,wv.w,acc[6][3]);
      acc[7][0]=fmaf(x1.w,wv.x,acc[7][0]); acc[7][1]=fmaf(x1.w,wv.y,acc[7][1]);
      acc[7][2]=fmaf(x1.w,wv.z,acc[7][2]); acc[7][3]=fmaf(x1.w,wv.w,acc[7][3]);
    }
  }

  const float4 asv = *reinterpret_cast<const float4*>(&asrc[c4]);
  const float4 adv = *reinterpret_cast<const float4*>(&adst[c4]);
  const int GT = 32 / H;
  int hh = tc / GT;

  #pragma unroll
  for (int r=0;r<8;r++){
    int gr = row0 + r8 + r;
    if (gr < n){
      *reinterpret_cast<float4*>(&Hout[(size_t)gr*128 + c4]) =
        make_float4(acc[r][0], acc[r][1], acc[r][2], acc[r][3]);
    }
    float ps = acc[r][0]*asv.x + acc[r][1]*asv.y + acc[r][2]*asv.z + acc[r][3]*asv.w;
    float pd = acc[r][0]*adv.x + acc[r][1]*adv.y + acc[r][2]*adv.z + acc[r][3]*adv.w;
    #pragma unroll
    for (int m=1;m<GT;m<<=1){ ps += __shfl_xor(ps,m); pd += __shfl_xor(pd,m); }
    if ((tc & (GT-1)) == 0 && gr < n){
      als[(size_t)gr*H + hh] = ps;
      ald[(size_t)gr*H + hh] = pd;
    }
  }
}

// ---------------- per-dst segment softmax + weighted aggregation ----------------
template<int H>
__global__ __launch_bounds__(256) void aggr(
    const float* __restrict__ h, const float* __restrict__ als,
    const float* __restrict__ ald, const int* __restrict__ srcs,
    const int* __restrict__ off, const float* __restrict__ bias,
    float* __restrict__ out, int n)
{
  __shared__ float s_p[4][64*H];
  __shared__ int   s_s[4][64];
  int tid = threadIdx.x;
  int wid = tid >> 6, lane = tid & 63;
  int d = blockIdx.x*4 + wid;
  if (d >= n) return;
  int half = lane >> 5, ch = lane & 31;
  int c4 = ch*4;
  const int hh = (H==1) ? 0 : (ch >> 3);

  int s0 = off[d], s1 = off[d+1];

  float adv[H];
  #pragma unroll
  for (int q=0;q<H;q++) adv[q] = ald[(size_t)d*H + q];

  float m[H], ssum[H];
  #pragma unroll
  for (int q=0;q<H;q++){ m[q] = -INFINITY; ssum[q] = 0.f; }
  float a0=0.f, a1=0.f, a2=0.f, a3=0.f;

  for (int base = s0; base < s1; base += 64){
    int cl = s1 - base; if (cl > 64) cl = 64;

    int sv = 0;
    float e[H];
    if (lane < cl){
      sv = srcs[base + lane];
      #pragma unroll
      for (int q=0;q<H;q++) e[q] = lrelu(als[(size_t)sv*H + q] + adv[q]);
    } else {
      #pragma unroll
      for (int q=0;q<H;q++) e[q] = -INFINITY;
    }

    float cm[H];
    #pragma unroll
    for (int q=0;q<H;q++) cm[q] = e[q];
    #pragma unroll
    for (int sh=1; sh<64; sh<<=1){
      #pragma unroll
      for (int q=0;q<H;q++) cm[q] = fmaxf(cm[q], __shfl_xor(cm[q], sh));
    }

    float p[H], sc[H];
    #pragma unroll
    for (int q=0;q<H;q++){
      float nm = fmaxf(m[q], cm[q]);
      sc[q] = __expf(m[q] - nm);
      ssum[q] *= sc[q];
      m[q] = nm;
      p[q] = __expf(e[q] - nm);
    }
    float schh = sc[0];
    #pragma unroll
    for (int q=1;q<H;q++) schh = (hh==q) ? sc[q] : schh;
    a0 *= schh; a1 *= schh; a2 *= schh; a3 *= schh;

    float cs[H];
    #pragma unroll
    for (int q=0;q<H;q++) cs[q] = p[q];
    #pragma unroll
    for (int sh=1; sh<64; sh<<=1){
      #pragma unroll
      for (int q=0;q<H;q++) cs[q] += __shfl_xor(cs[q], sh);
    }
    #pragma unroll
    for (int q=0;q<H;q++) ssum[q] += cs[q];

    #pragma unroll
    for (int q=0;q<H;q++) s_p[wid][lane*H + q] = p[q];
    s_s[wid][lane] = sv;

    for (int j = half; j < cl; j += 2){
      int s = s_s[wid][j];
      float w = s_p[wid][j*H + hh];
      const float4 hv = *reinterpret_cast<const float4*>(&h[(size_t)s*128 + c4]);
      a0 = fmaf(w, hv.x, a0);
      a1 = fmaf(w, hv.y, a1);
      a2 = fmaf(w, hv.z, a2);
      a3 = fmaf(w, hv.w, a3);
    }
  }

  a0 += __shfl_xor(a0, 32);
  a1 += __shfl_xor(a1, 32);
  a2 += __shfl_xor(a2, 32);
  a3 += __shfl_xor(a3, 32);

  float den = ssum[0];
  #pragma unroll
  for (int q=1;q<H;q++) den = (hh==q) ? ssum[q] : den;
  float inv = 1.f / den;

  if (half == 0){
    const float4 bv = *reinterpret_cast<const float4*>(&bias[c4]);
    float4 o;
    o.x = elu_(a0*inv + bv.x);
    o.y = elu_(a1*inv + bv.y);
    o.z = elu_(a2*inv + bv.z);
    o.w = elu_(a3*inv + bv.w);
    *reinterpret_cast<float4*>(&out[(size_t)d*128 + c4]) = o;
  }
}

// ---------------- global mean pool (batch is sorted) ----------------
__global__ __launch_bounds__(256) void kpool(const float* __restrict__ act,
    const int* __restrict__ batch, int n, float* __restrict__ pool)
{
  __shared__ int sb[2];
  __shared__ float part[128];
  int g = blockIdx.x, tid = threadIdx.x;
  if (tid == 0){
    int lo=0, hi=n;
    while (lo<hi){ int mid=(lo+hi)>>1; if (batch[mid] < g) lo=mid+1; else hi=mid; }
    sb[0]=lo;
    int lo2=lo, hi2=n;
    while (lo2<hi2){ int mid=(lo2+hi2)>>1; if (batch[mid] < g+1) lo2=mid+1; else hi2=mid; }
    sb[1]=lo2;
  }
  __syncthreads();
  int lo=sb[0], hi=sb[1];
  int c = tid & 127, half = tid >> 7;
  float acc = 0.f;
  for (int i=lo+half; i<hi; i+=2) acc += act[(size_t)i*128 + c];
  if (half == 0) part[c] = acc;
  __syncthreads();
  if (half == 1) part[c] += acc;
  __syncthreads();
  if (half == 0){
    float cnt = (float)(hi-lo);
    pool[(size_t)g*128 + c] = part[c] / fmaxf(cnt, 1.f);
  }
}

// ---------------- classifier head ----------------
__global__ __launch_bounds__(64) void kclassify(const float* __restrict__ pool,
    const float* __restrict__ Wc1, const float* __restrict__ bc1,
    const float* __restrict__ Wc2, const float* __restrict__ bc2,
    float* __restrict__ logits)
{
  int g = blockIdx.x, j = threadIdx.x;
  const float* hp = pool + (size_t)g*128;
  float t = bc1[j];
  #pragma unroll 8
  for (int c=0;c<128;c++) t = fmaf(hp[c], Wc1[c*64+j], t);
  t = fmaxf(t, 0.f) * Wc2[j];
  for (int m=1;m<64;m<<=1) t += __shfl_xor(t, m);
  if (j==0) logits[g] = t + bc2[0];
}

extern "C" void kernel_launch(void* const* d_in, const int* in_sizes, int n_in,
                              void* d_out, int out_size, void* d_ws, size_t ws_size,
                              hipStream_t stream)
{
  const int*   x_lex = (const int*)d_in[0];
  const int*   ei    = (const int*)d_in[1];
  const int*   batch = (const int*)d_in[2];
  const float* emb   = (const float*)d_in[3];
  const float* W1    = (const float*)d_in[4];
  const float* a1s   = (const float*)d_in[5];
  const float* a1d   = (const float*)d_in[6];
  const float* b1    = (const float*)d_in[7];
  const float* W2    = (const float*)d_in[8];
  const float* a2s   = (const float*)d_in[9];
  const float* a2d   = (const float*)d_in[10];
  const float* b2    = (const float*)d_in[11];
  const float* Wc1   = (const float*)d_in[12];
  const float* bc1   = (const float*)d_in[13];
  const float* Wc2   = (const float*)d_in[14];
  const float* bc2   = (const float*)d_in[15];

  int N = in_sizes[0];
  int E = in_sizes[1] / 2;
  int Etot = E + N;
  const int G = 256;

  char* p = (char*)d_ws;
  float* hbuf   = (float*)p;          p += (size_t)N*128*4;
  float* act    = (float*)p;          p += (size_t)N*128*4;
  float* als    = (float*)p;          p += (size_t)N*4*4;
  float* ald    = (float*)p;          p += (size_t)N*4*4;
  int*   off    = (int*)p;            p += (size_t)(N+1)*4;
  int*   srcs   = (int*)p;            p += (size_t)Etot*4;
  int*   totals = (int*)p;            p += NBKT*4;
  int*   bbase  = (int*)p;            p += (NBKT+1)*4;
  int*   bcur   = (int*)p;            /* NBKT ints */
  int2*  tmp    = (int2*)hbuf;        // aliases hbuf: CSR build finishes before gemm writes hbuf

  // ---- CSR build (bucket sort, shared by both GAT layers) ----
  hipMemsetAsync(totals, 0, NBKT*4, stream);
  int nblk = (Etot + P_CHUNK - 1) / P_CHUNK;
  int nb   = (N + 127) / 128;
  p1hist   <<<nblk,256,0,stream>>>(ei, E, Etot, totals);
  p2scan   <<<1,   256,0,stream>>>(totals, bbase, bcur, Etot, off, N);
  p3scatter<<<nblk,256,0,stream>>>(ei, E, Etot, bcur, tmp);
  p4local  <<<nb,  256,0,stream>>>(tmp, bbase, off, srcs, N);

  // ---- layer 1: h = emb[x_lex] @ W1, 4 heads ----
  int gb = (N + 63)/64;
  gemm_al<4,true ><<<gb,256,0,stream>>>(emb, x_lex, W1, a1s, a1d, hbuf, als, ald, N);
  aggr<4><<<(N+3)/4,256,0,stream>>>(hbuf, als, ald, srcs, off, b1, act, N);

  // ---- layer 2: h2 = act @ W2, 1 head ----
  gemm_al<1,false><<<gb,256,0,stream>>>(act, nullptr, W2, a2s, a2d, hbuf, als, ald, N);
  aggr<1><<<(N+3)/4,256,0,stream>>>(hbuf, als, ald, srcs, off, b2, act, N);

  // ---- pool + classifier ----
  float* out = (float*)d_out;
  kpool<<<G,256,0,stream>>>(act, batch, N, out + G);
  kclassify<<<G,64,0,stream>>>(out + G, Wc1, bc1, Wc2, bc2, out);
}